// Round 17
// baseline (187.590 us; speedup 1.0000x reference)
//
#include <hip/hip_runtime.h>
#include <cmath>

#define TAPE_SZ 100000
#define N_SZ    50000
#define F_SZ    32
#define B_SZ    128
#define GSUB    32         // b's per group: row-segment = 32*2B = one 64-B granule
#define NGRP    4          // groups; g=blockIdx&3 -> 2 XCDs share each 6.4-MB slice
#define NBV     64         // n's per gather block
#define NCHUNK  ((N_SZ + NBV - 1) / NBV)   // 782
#define GRID_G  (NCHUNK * NGRP)            // 3128

// Manual round-to-nearest-even f32 -> bf16 bits.
static __device__ __forceinline__ unsigned short f32_to_bf16(float f) {
    unsigned int u = __float_as_uint(f);
    u = (u + 0x7fffu + ((u >> 16) & 1u)) >> 16;
    return (unsigned short)u;
}

// ---------------------------------------------------------------------------
// Transpose tape (B x TAPE fp32) -> tapeG[g][row][32b] bf16 (g = b/32).
// R14-verified. fp32 tail (cols >= N_SZ) fused via per-column guard.
// ---------------------------------------------------------------------------
__global__ __launch_bounds__(256) void transpose_g32(const float* __restrict__ in,
                                                     unsigned short* __restrict__ outG,
                                                     float* __restrict__ out) {
    __shared__ float tile[32][129];
    const int x0 = blockIdx.x * 32;
    const int tx = threadIdx.x;       // tape-col 0..31
    const int ty = threadIdx.y;       // 0..7

    #pragma unroll
    for (int yy = ty; yy < B_SZ; yy += 8)
        tile[tx][yy] = in[(size_t)yy * TAPE_SZ + x0 + tx];
    __syncthreads();

    const int tid = ty * 32 + tx;
    const int l = tid >> 3;           // row-in-tile 0..31
    const int o = tid & 7;            // 16-b chunk 0..7
    const int g = o >> 1;             // b-group 0..3
    const int hf = o & 1;             // half of group
    unsigned short* dst = outG + ((size_t)g * TAPE_SZ + x0 + l) * GSUB + hf * 16;
    union { unsigned short u[8]; uint4 q; } p0, p1;
    #pragma unroll
    for (int k = 0; k < 8; ++k) {
        p0.u[k] = f32_to_bf16(tile[l][g * GSUB + hf * 16 + k]);
        p1.u[k] = f32_to_bf16(tile[l][g * GSUB + hf * 16 + 8 + k]);
    }
    *(uint4*)dst       = p0.q;
    *(uint4*)(dst + 8) = p1.q;

    // ---- fp32 tail: columns [N_SZ, TAPE_SZ) survive into out (per-column) ----
    if (x0 + tx >= N_SZ) {
        #pragma unroll
        for (int yy = ty; yy < B_SZ; yy += 8)
            out[(size_t)yy * TAPE_SZ + x0 + tx] = tile[tx][yy];
    }
}

// ---------------------------------------------------------------------------
// Gather-matmul: R14's proven core, single pass (half-split removed).
// Block = (chunk of 64 n, g). g=blockIdx&3 -> each XCD pair serves one 6.4-MB
// group slice (R14 measured per-kernel tape traffic ~25 MB with this pinning
// vs 179 MB unpartitioned in R16). Thread = (nl, seg): one 64-B granule per
// (n,f) -> 6.4M probes (floor). Batch-8 loads (MLP 8, VGPR uncapped as R14).
// Single VALU pass, single staging pass, no acc round-trip.
// ---------------------------------------------------------------------------
__global__ __launch_bounds__(256) void gather_full(
    const unsigned short* __restrict__ tapeG,
    const float* __restrict__ weights,
    const float* __restrict__ bias,
    const int*   __restrict__ in_idx,
    const int*   __restrict__ out_idx,
    const int*   __restrict__ act_type,
    float* __restrict__ out) {
    __shared__ union {
        int2  iw[NBV][33];     // (.x = row, .y = weight bits); pitch 33
        float x[GSUB][66];     // epilogue stage [b_local][n], aliased
    } u;
    __shared__ float s_bias[NBV];
    __shared__ int   s_act[NBV];
    __shared__ int   s_oidx[NBV];

    const int tid   = threadIdx.x;
    const int g     = blockIdx.x & 3;     // b-group; XCD&3 under %8 round-robin
    const int chunk = blockIdx.x >> 2;
    const int n0    = chunk * NBV;
    const int nend  = min(NBV, N_SZ - n0);

    for (int t = tid; t < nend * 32; t += 256) {
        const int n = t >> 5, f = t & 31;
        u.iw[n][f] = make_int2(in_idx[(size_t)n0 * 32 + t],
                               __float_as_int(weights[(size_t)n0 * 32 + t]));
    }
    if (tid < nend) {
        s_bias[tid] = bias[n0 + tid];
        s_act[tid]  = act_type[n0 + tid];
        s_oidx[tid] = out_idx[n0 + tid];
    }
    __syncthreads();

    const int nl  = tid >> 2;             // n_local 0..63
    const int seg = tid & 3;              // granule segment: b_sub = 8*seg .. 8*seg+7
    const bool an = (nl < nend);
    const unsigned short* tg = tapeG + (size_t)g * TAPE_SZ * GSUB + seg * 8;

    float a[8];
    #pragma unroll
    for (int k = 0; k < 8; ++k) a[k] = 0.f;

    #pragma unroll
    for (int fo = 0; fo < 32; fo += 8) {
        int r8[8]; float w8[8];
        #pragma unroll
        for (int j = 0; j < 8; ++j) {
            const int2 iw = u.iw[nl][fo + j];
            r8[j] = iw.x; w8[j] = __int_as_float(iw.y);
        }
        uint4 q8[8];
        #pragma unroll
        for (int j = 0; j < 8; ++j) {
            q8[j] = make_uint4(0u, 0u, 0u, 0u);
            if (an) q8[j] = *(const uint4*)(tg + (size_t)r8[j] * GSUB);
        }
        #pragma unroll
        for (int j = 0; j < 8; ++j) {
            const float wv = w8[j];
            a[0] = fmaf(__uint_as_float(q8[j].x << 16),         wv, a[0]);
            a[1] = fmaf(__uint_as_float(q8[j].x & 0xffff0000u), wv, a[1]);
            a[2] = fmaf(__uint_as_float(q8[j].y << 16),         wv, a[2]);
            a[3] = fmaf(__uint_as_float(q8[j].y & 0xffff0000u), wv, a[3]);
            a[4] = fmaf(__uint_as_float(q8[j].z << 16),         wv, a[4]);
            a[5] = fmaf(__uint_as_float(q8[j].z & 0xffff0000u), wv, a[5]);
            a[6] = fmaf(__uint_as_float(q8[j].w << 16),         wv, a[6]);
            a[7] = fmaf(__uint_as_float(q8[j].w & 0xffff0000u), wv, a[7]);
        }
    }

    // ---- bias + activation ----
    if (an) {
        const float bz = s_bias[nl];
        const int   at = s_act[nl];
        #pragma unroll
        for (int k = 0; k < 8; ++k) {
            const float v = a[k] + bz;
            a[k] = (at == 0) ? fmaxf(v, 0.f) : tanhf(v);
        }
    }
    __syncthreads();   // all iw reads complete before aliased x writes
    if (an) {
        #pragma unroll
        for (int k = 0; k < 8; ++k) u.x[seg * 8 + k][nl] = a[k];
    }
    __syncthreads();

    // ---- epilogue: coalesced float4 row stores (consec out_idx fast path) ----
    const int quads = (nend + 3) >> 2;
    for (int it = tid; it < GSUB * quads; it += 256) {
        int bl, j4;
        if (nend == NBV) { bl = it >> 4; j4 = it & 15; }
        else             { bl = it / quads; j4 = it - bl * quads; }
        const int nq  = j4 * 4;
        const int oc0 = s_oidx[nq];
        float* orow = out + (size_t)(g * GSUB + bl) * TAPE_SZ;
        const bool consec = (nq + 3 < nend) &&
                            (s_oidx[nq + 1] == oc0 + 1) &&
                            (s_oidx[nq + 2] == oc0 + 2) &&
                            (s_oidx[nq + 3] == oc0 + 3) && ((oc0 & 3) == 0);
        if (consec) {
            *(float4*)(orow + oc0) = make_float4(u.x[bl][nq + 0], u.x[bl][nq + 1],
                                                 u.x[bl][nq + 2], u.x[bl][nq + 3]);
        } else {
            #pragma unroll
            for (int c = 0; c < 4; ++c)
                if (nq + c < nend) orow[s_oidx[nq + c]] = u.x[bl][nq + c];
        }
    }
}

// ---------------------------------------------------------------------------
// Fallback (workspace too small): direct uncoalesced gather. Correct, slow.
// ---------------------------------------------------------------------------
__global__ __launch_bounds__(128) void gather_fallback(const float* __restrict__ tape,
                                                       const float* __restrict__ weights,
                                                       const float* __restrict__ bias,
                                                       const int*   __restrict__ in_idx,
                                                       const int*   __restrict__ out_idx,
                                                       const int*   __restrict__ act_type,
                                                       float* __restrict__ out) {
    const int n = blockIdx.x;
    const int b = threadIdx.x;
    float acc = 0.f;
    for (int f = 0; f < F_SZ; ++f) {
        acc += tape[(size_t)b * TAPE_SZ + in_idx[(size_t)n * F_SZ + f]] *
               weights[(size_t)n * F_SZ + f];
    }
    acc += bias[n];
    acc = (act_type[n] == 0) ? fmaxf(acc, 0.f) : tanhf(acc);
    out[(size_t)b * TAPE_SZ + out_idx[n]] = acc;
}

__global__ __launch_bounds__(256) void copy_tail_fb(const float* __restrict__ tape,
                                                    float* __restrict__ out) {
    const int n4 = (TAPE_SZ - N_SZ) / 4;
    int i = blockIdx.x * blockDim.x + threadIdx.x;
    int b = blockIdx.y;
    if (i < n4) {
        const float4* src = (const float4*)(tape + (size_t)b * TAPE_SZ + N_SZ);
        float4*       dst = (float4*)(out  + (size_t)b * TAPE_SZ + N_SZ);
        dst[i] = src[i];
    }
}

extern "C" void kernel_launch(void* const* d_in, const int* in_sizes, int n_in,
                              void* d_out, int out_size, void* d_ws, size_t ws_size,
                              hipStream_t stream) {
    const float* tape    = (const float*)d_in[0];
    const float* weights = (const float*)d_in[1];
    const float* bias    = (const float*)d_in[2];
    const int*   in_idx  = (const int*)d_in[3];
    const int*   out_idx = (const int*)d_in[4];
    const int*   act     = (const int*)d_in[5];
    float*       out     = (float*)d_out;

    const size_t need = (size_t)TAPE_SZ * B_SZ * sizeof(unsigned short);   // 25.6 MB
    if (ws_size >= need) {
        unsigned short* tapeG = (unsigned short*)d_ws;
        transpose_g32<<<dim3(TAPE_SZ / 32), dim3(32, 8), 0, stream>>>(tape, tapeG, out);
        gather_full<<<dim3(GRID_G), dim3(256), 0, stream>>>(
            tapeG, weights, bias, in_idx, out_idx, act, out);
    } else {
        copy_tail_fb<<<dim3(((TAPE_SZ - N_SZ) / 4 + 255) / 256, B_SZ), 256, 0, stream>>>(tape, out);
        gather_fallback<<<dim3(N_SZ), 128, 0, stream>>>(
            tape, weights, bias, in_idx, out_idx, act, out);
    }
}